// Round 12
// baseline (182.981 us; speedup 1.0000x reference)
//
#include <hip/hip_runtime.h>

#define NPTS 1048576
#define NOUT 128
#define NPAR 64
#define BLOCK 256
#define RPB 16             // output rows per block
#define NGRP (NOUT / RPB)  // 8 row-groups
#define PPB 2048           // points per block
#define STRIPS (NPTS / PPB) // 512 strips
#define PROW 24            // params LDS row stride in shorts (48 B: 16B-aligned halves, rows cycle 8 bank-groups)

typedef float vf4 __attribute__((ext_vector_type(4)));

__device__ __forceinline__ unsigned short f2bf(float f) {
    unsigned int u = __float_as_uint(f);
    u += 0x7fffu + ((u >> 16) & 1u);   // RNE
    return (unsigned short)(u >> 16);
}

__device__ __forceinline__ void bf2x(unsigned int u, float& lo, float& hi) {
    lo = __uint_as_float(u << 16);
    hi = __uint_as_float(u & 0xffff0000u);
}

__global__ __launch_bounds__(BLOCK, 4)
void kan_kernel(const float* __restrict__ x,
                const float* __restrict__ params,
                float* __restrict__ out) {
    __shared__ unsigned short sP[NPAR * PROW];   // 3 KiB: 64 rows x 16 cols (this group's cols)

    const int tid   = threadIdx.x;
    const int g     = blockIdx.x >> 9;           // row-group (SLOW index -> resident blocks share few groups)
    const int strip = blockIdx.x & (STRIPS - 1); // point strip (FAST -> neighbors write adjacent addresses)
    const int j0    = g * RPB;

    // Stage this group's 16 param columns, all 64 rows, as bf16.
    {
        const int row  = tid >> 2;
        const int quad = tid & 3;
        float4 v = *(const float4*)(params + row * NOUT + j0 + quad * 4);
        ushort4 h;
        h.x = f2bf(v.x); h.y = f2bf(v.y); h.z = f2bf(v.z); h.w = f2bf(v.w);
        *(ushort4*)&sP[row * PROW + quad * 4] = h;
    }
    __syncthreads();

    #pragma unroll 1
    for (int ch = 0; ch < 2; ++ch) {
        const int base = strip * PPB + ch * 1024 + tid * 4;
        const float4 xv = *(const float4*)(x + base);
        float xs[4] = {xv.x, xv.y, xv.z, xv.w};

        float b[4][4], sil[4];
        int rbase[4];

        #pragma unroll
        for (int pp = 0; pp < 4; ++pp) {
            float xx = xs[pp];
            sil[pp] = xx / (1.0f + __expf(-xx));

            float inr = (xx >= -3.0f && xx < 3.0f) ? 1.0f : 0.0f;
            float u = (xx + 3.0f) * 10.0f;
            int si = (int)u;
            si = si < 0 ? 0 : (si > 59 ? 59 : si);

            float Ki   = -3.0f + 0.1f * (float)si;
            float Kim1 = -3.0f + 0.1f * (float)(si - 1 > 0 ? si - 1 : 0);
            float Kim2 = -3.0f + 0.1f * (float)(si - 2 > 0 ? si - 2 : 0);
            float Kip1 = -3.0f + 0.1f * (float)(si + 1);
            float Kip2 = -3.0f + 0.1f * (float)(si + 2 < 60 ? si + 2 : 60);
            float Kip3 = -3.0f + 0.1f * (float)(si + 3 < 60 ? si + 3 : 60);

            float l1 = xx - Ki,   r1 = Kip1 - xx;
            float l2 = xx - Kim1, r2 = Kip2 - xx;
            float l3 = xx - Kim2, r3 = Kip3 - xx;

            float N0 = 1.0f, N1, N2, N3, t, saved;
            t = N0 / (r1 + l1); N0 = r1 * t; N1 = l1 * t;
            t = N0 / (r1 + l2); N0 = r1 * t;          saved = l2 * t;
            t = N1 / (r2 + l1); N1 = saved + r2 * t;  N2    = l1 * t;
            t = N0 / (r1 + l3); N0 = r1 * t;          saved = l3 * t;
            t = N1 / (r2 + l2); N1 = saved + r2 * t;  saved = l2 * t;
            t = N2 / (r3 + l1); N2 = saved + r3 * t;  N3    = l1 * t;

            b[pp][0] = N0 * inr;
            b[pp][1] = N1 * inr;
            b[pp][2] = N2 * inr;
            b[pp][3] = N3 * inr;
            rbase[pp] = si;
        }

        // Two column-halves of 8 (keeps accumulator live-set at 32 regs).
        #pragma unroll
        for (int h = 0; h < 2; ++h) {
            uint4 u63 = *(const uint4*)&sP[63 * PROW + h * 8];
            float p63f[8];
            bf2x(u63.x, p63f[0], p63f[1]); bf2x(u63.y, p63f[2], p63f[3]);
            bf2x(u63.z, p63f[4], p63f[5]); bf2x(u63.w, p63f[6], p63f[7]);

            float a[4][8];
            #pragma unroll
            for (int pp = 0; pp < 4; ++pp) {
                float s = sil[pp];
                float acc[8];
                #pragma unroll
                for (int c = 0; c < 8; ++c) acc[c] = s * p63f[c];
                #pragma unroll
                for (int r = 0; r < 4; ++r) {
                    uint4 q = *(const uint4*)&sP[(rbase[pp] + r) * PROW + h * 8];
                    float f[8];
                    bf2x(q.x, f[0], f[1]); bf2x(q.y, f[2], f[3]);
                    bf2x(q.z, f[4], f[5]); bf2x(q.w, f[6], f[7]);
                    float br = b[pp][r];
                    #pragma unroll
                    for (int c = 0; c < 8; ++c) acc[c] = fmaf(br, f[c], acc[c]);
                }
                #pragma unroll
                for (int c = 0; c < 8; ++c) a[pp][c] = acc[c];
            }

            // Coalesced vf4 stores; block's rows only -> dense chip-wide frontier.
            #pragma unroll
            for (int c = 0; c < 8; ++c) {
                vf4 v = { a[0][c], a[1][c], a[2][c], a[3][c] };
                *(vf4*)(out + (size_t)(j0 + h * 8 + c) * NPTS + base) = v;
            }
        }
    }
}

extern "C" void kernel_launch(void* const* d_in, const int* in_sizes, int n_in,
                              void* d_out, int out_size, void* d_ws, size_t ws_size,
                              hipStream_t stream) {
    const float* x      = (const float*)d_in[0];
    const float* params = (const float*)d_in[1];
    float* out          = (float*)d_out;

    dim3 grid(NGRP * STRIPS);   // 4096 blocks: row-group slow, strip fast
    kan_kernel<<<grid, BLOCK, 0, stream>>>(x, params, out);
}

// Round 13
// 120.176 us; speedup vs baseline: 1.5226x; 1.5226x over previous
//
#include <hip/hip_runtime.h>

#define NPTS 1048576
#define NOUT 128
#define NPAR 64
#define BLOCK 256
#define PPT 4              // points per thread
#define CPB (BLOCK * PPT)  // 1024 points per block
#define STRH 136           // params LDS row stride in bf16 (272 B = 17*16, rows cycle 8 bank groups)
#define G 8                // output rows staged per tile
#define SST 1024           // staging row stride in f32 (both access phases conflict-free by construction)

typedef float vf4 __attribute__((ext_vector_type(4)));

__device__ __forceinline__ unsigned short f2bf(float f) {
    unsigned int u = __float_as_uint(f);
    u += 0x7fffu + ((u >> 16) & 1u);   // round-to-nearest-even
    return (unsigned short)(u >> 16);
}

__device__ __forceinline__ void bf2x(unsigned int u, float& lo, float& hi) {
    lo = __uint_as_float(u << 16);
    hi = __uint_as_float(u & 0xffff0000u);
}

__global__ __launch_bounds__(BLOCK, 4)
void kan_kernel(const float* __restrict__ x,
                const float* __restrict__ params,
                float* __restrict__ out) {
    __shared__ unsigned short sH[NPAR * STRH];  // 17.4 KB params (bf16)
    __shared__ float sS[G * SST];               // 32 KB output staging

    const int tid = threadIdx.x;

    // Stage params [64][128] f32 -> LDS bf16
    {
        const float4* p4 = (const float4*)params;
        #pragma unroll
        for (int g = tid; g < NPAR * (NOUT / 4); g += BLOCK) {
            float4 v = p4[g];
            ushort4 h;
            h.x = f2bf(v.x); h.y = f2bf(v.y); h.z = f2bf(v.z); h.w = f2bf(v.w);
            *(ushort4*)&sH[(g >> 5) * STRH + (g & 31) * 4] = h;
        }
    }

    const int base = blockIdx.x * CPB + tid * PPT;
    const float4 xv = *(const float4*)(x + base);
    float xs[PPT] = {xv.x, xv.y, xv.z, xv.w};

    float b[PPT][4];
    float sil[PPT];
    int   rbase[PPT];

    #pragma unroll
    for (int pp = 0; pp < PPT; ++pp) {
        float xx = xs[pp];
        sil[pp] = xx / (1.0f + __expf(-xx));

        float inr = (xx >= -3.0f && xx < 3.0f) ? 1.0f : 0.0f;
        float u = (xx + 3.0f) * 10.0f;   // interior knot spacing = 0.1
        int si = (int)u;
        si = si < 0 ? 0 : (si > 59 ? 59 : si);

        float Ki   = -3.0f + 0.1f * (float)si;
        float Kim1 = -3.0f + 0.1f * (float)(si - 1 > 0 ? si - 1 : 0);
        float Kim2 = -3.0f + 0.1f * (float)(si - 2 > 0 ? si - 2 : 0);
        float Kip1 = -3.0f + 0.1f * (float)(si + 1);
        float Kip2 = -3.0f + 0.1f * (float)(si + 2 < 60 ? si + 2 : 60);
        float Kip3 = -3.0f + 0.1f * (float)(si + 3 < 60 ? si + 3 : 60);

        float l1 = xx - Ki,   r1 = Kip1 - xx;
        float l2 = xx - Kim1, r2 = Kip2 - xx;
        float l3 = xx - Kim2, r3 = Kip3 - xx;

        float N0 = 1.0f, N1, N2, N3, t, saved;
        t = N0 / (r1 + l1); N0 = r1 * t; N1 = l1 * t;
        t = N0 / (r1 + l2); N0 = r1 * t;          saved = l2 * t;
        t = N1 / (r2 + l1); N1 = saved + r2 * t;  N2    = l1 * t;
        t = N0 / (r1 + l3); N0 = r1 * t;          saved = l3 * t;
        t = N1 / (r2 + l2); N1 = saved + r2 * t;  saved = l2 * t;
        t = N2 / (r3 + l1); N2 = saved + r3 * t;  N3    = l1 * t;

        b[pp][0] = N0 * inr;
        b[pp][1] = N1 * inr;
        b[pp][2] = N2 * inr;
        b[pp][3] = N3 * inr;
        rbase[pp] = si;
    }

    __syncthreads();   // params staged

    const int w = tid >> 6;       // wave id (0..3)
    const int l = tid & 63;       // lane

    #pragma unroll 1
    for (int j0 = 0; j0 < NOUT; j0 += G) {
        // ---- compute phase: 8 cols for 4 points ----
        uint4 u63 = *(const uint4*)&sH[63 * STRH + j0];
        float p63f[8];
        bf2x(u63.x, p63f[0], p63f[1]);
        bf2x(u63.y, p63f[2], p63f[3]);
        bf2x(u63.z, p63f[4], p63f[5]);
        bf2x(u63.w, p63f[6], p63f[7]);

        float a[PPT][8];
        #pragma unroll
        for (int pp = 0; pp < PPT; ++pp) {
            const unsigned short* rp = &sH[rbase[pp] * STRH + j0];
            float s = sil[pp];
            float acc[8];
            #pragma unroll
            for (int c = 0; c < 8; ++c) acc[c] = s * p63f[c];

            #pragma unroll
            for (int r = 0; r < 4; ++r) {
                uint4 q = *(const uint4*)(rp + r * STRH);
                float f[8];
                bf2x(q.x, f[0], f[1]); bf2x(q.y, f[2], f[3]);
                bf2x(q.z, f[4], f[5]); bf2x(q.w, f[6], f[7]);
                float br = b[pp][r];
                #pragma unroll
                for (int c = 0; c < 8; ++c) acc[c] = fmaf(br, f[c], acc[c]);
            }
            #pragma unroll
            for (int c = 0; c < 8; ++c) a[pp][c] = acc[c];
        }

        // write staging: row c holds this block's 1024 points for output row j0+c
        #pragma unroll
        for (int c = 0; c < 8; ++c) {
            vf4 v = { a[0][c], a[1][c], a[2][c], a[3][c] };
            *(vf4*)&sS[c * SST + tid * 4] = v;
        }

        __syncthreads();

        // ---- drain phase: j-major, one 4 KiB contiguous row burst per wave-row ----
        #pragma unroll
        for (int rr = 0; rr < 2; ++rr) {
            const int r = 2 * w + rr;
            float* orow = out + (size_t)(j0 + r) * NPTS + blockIdx.x * CPB;
            #pragma unroll
            for (int k = 0; k < 4; ++k) {
                vf4 v = *(const vf4*)&sS[r * SST + k * 256 + l * 4];
                *(vf4*)(orow + k * 256 + l * 4) = v;
            }
        }

        __syncthreads();   // staging reusable
    }
}

extern "C" void kernel_launch(void* const* d_in, const int* in_sizes, int n_in,
                              void* d_out, int out_size, void* d_ws, size_t ws_size,
                              hipStream_t stream) {
    const float* x      = (const float*)d_in[0];
    const float* params = (const float*)d_in[1];
    float* out          = (float*)d_out;

    dim3 grid(NPTS / CPB);   // 1024 blocks
    kan_kernel<<<grid, BLOCK, 0, stream>>>(x, params, out);
}